// Round 16
// baseline (5017.746 us; speedup 1.0000x reference)
//
#include <hip/hip_runtime.h>
#include <hip/hip_bf16.h>
#include <stdint.h>

typedef short short8 __attribute__((ext_vector_type(8)));
typedef float f32x4  __attribute__((ext_vector_type(4)));
typedef float fvec4  __attribute__((ext_vector_type(4)));

#define SCOPE_AGENT __HIP_MEMORY_SCOPE_AGENT
#define MFMA(a,b,c) __builtin_amdgcn_mfma_f32_16x16x32_bf16((a),(b),(c),0,0,0)

constexpr int nT = 1024, nD = 256, nH = 512, nO = 256;
constexpr int SLOT_ELEMS = 64 * 1024;                 // 64 rows x (512 hi | 512 lo) bf16
constexpr size_t SLOT_BYTES = (size_t)SLOT_ELEMS * 2; // 128 KiB
constexpr int FPAD = 32;                              // ints per counter (128B line)
constexpr size_t FLAGS_BYTES = 256 * FPAD * 4;        // 32 KiB
constexpr size_t RING_OFF = FLAGS_BYTES + 8192;

// R15 post-mortem: watermark+h1-hoist -7%; remaining excess = producer tail
// (barrier over slowest drain + serialized tid0 flag store) + straggler max
// over 32 producers per poll. R16: dependency-narrowed, barrier-free
// rendezvous (one coherent protocol change):
//  - COUNTER flags: each wave drains its OWN stores then fetch_add(+1);
//    "block done step t" = counter >= 4(t+1). No post-store barrier, no
//    serialized flag store.
//  - PER-WAVE narrow polls: wave w consumes cols from exactly 8 producer
//    blocks (ns in [8w,8w+8)); it polls only those 8 counters, no barrier.
//    Straggler width 32->8; each wave's load+MFMA starts when ITS producers
//    are done. L1 h1 + L0 backpressure via cached watermarks.
//  - 2 barriers/step (glds-protect + reduce), both AFTER poll+load+MFMA.
// Arithmetic identical -> absmax must stay exactly 4.882812e-4.
#define K4(M)  M(0) M(1) M(2) M(3)
#define GK2(M) M(0,0) M(1,0) M(2,0) M(3,0) M(0,1) M(1,1) M(2,1) M(3,1)
#define GK4(M) GK2(M) M(0,2) M(1,2) M(2,2) M(3,2) M(0,3) M(1,3) M(2,3) M(3,3)

__device__ __forceinline__ float sigm(float x){ return 1.f/(1.f + __expf(-x)); }

__device__ __forceinline__ short8 cvt8h(const float* p){
  fvec4 a = *(const fvec4*)p;
  fvec4 b = *(const fvec4*)(p + 4);
  short8 hi;
  #pragma unroll
  for (int j = 0; j < 8; j++){
    float v = (j < 4) ? a[j] : b[j-4];
    hi[j] = (short)__bfloat16_as_ushort(__float2bfloat16(v));
  }
  return hi;
}
__device__ __forceinline__ void cvt8(const float* p, short8& hi, short8& lo){
  fvec4 a = *(const fvec4*)p;
  fvec4 b = *(const fvec4*)(p + 4);
  #pragma unroll
  for (int j = 0; j < 8; j++){
    float v = (j < 4) ? a[j] : b[j-4];
    __hip_bfloat16 h = __float2bfloat16(v);
    float r = v - __bfloat162float(h);
    hi[j] = (short)__bfloat16_as_ushort(h);
    lo[j] = (short)__bfloat16_as_ushort(__float2bfloat16(r));
  }
}
__device__ __forceinline__ unsigned pack2(float a, float b){
  return (unsigned)__bfloat16_as_ushort(__float2bfloat16(a)) |
         ((unsigned)__bfloat16_as_ushort(__float2bfloat16(b)) << 16);
}
__device__ __forceinline__ unsigned pack2lo(float a, float b){
  float ra = a - __bfloat162float(__float2bfloat16(a));
  float rb = b - __bfloat162float(__float2bfloat16(b));
  return pack2(ra, rb);
}

// h load: FAST = plain cached (L2-shareable); slow = agent atomic (proven)
template<int FAST>
__device__ __forceinline__ short8 ldh(const short* p){
  if constexpr (FAST){
    return *(const short8*)p;
  } else {
    union { unsigned long long u[2]; short8 v; } r;
    const unsigned long long* q = (const unsigned long long*)p;
    r.u[0] = __hip_atomic_load(q,     __ATOMIC_RELAXED, SCOPE_AGENT);
    r.u[1] = __hip_atomic_load(q + 1, __ATOMIC_RELAXED, SCOPE_AGENT);
    return r.v;
  }
}

// per-wave poll (NO barrier): p is a per-lane counter pointer; wait all >= cmp
__device__ __forceinline__ void pollN(const int* p, int cmp){
  int spins = 0;
  for(;;){
    int v = __hip_atomic_load(p, __ATOMIC_RELAXED, SCOPE_AGENT);
    if (__all(v >= cmp)) break;
    if (++spins > (1<<17)) break;                // fail-safe, never hang
    if (spins > 64) __builtin_amdgcn_s_sleep(1);
  }
}
// per-wave watermark: wait all >= cmp, return min completed step (c/4 - 1)
__device__ __forceinline__ int wmN(const int* p, int cmp){
  int v; int spins = 0;
  for(;;){
    v = __hip_atomic_load(p, __ATOMIC_RELAXED, SCOPE_AGENT);
    if (__all(v >= cmp)) break;
    if (++spins > (1<<17)) break;
    if (spins > 64) __builtin_amdgcn_s_sleep(1);
  }
  int m = v;
  #pragma unroll
  for (int off = 32; off; off >>= 1) m = min(m, __shfl_xor(m, off));
  return (m >> 2) - 1;
}

template<int FAST>
__global__ __launch_bounds__(256, 1)
__attribute__((amdgpu_waves_per_eu(1, 1)))
void lstm_kernel(
    const float* __restrict__ x,
    const float* __restrict__ Wih0, const float* __restrict__ Whh0,
    const float* __restrict__ bih0, const float* __restrict__ bhh0,
    const float* __restrict__ Wih1, const float* __restrict__ Whh1,
    const float* __restrict__ bih1, const float* __restrict__ bhh1,
    const float* __restrict__ fcw, const float* __restrict__ fcb,
    float* __restrict__ out,
    short* __restrict__ h1r, short* __restrict__ h2r,
    float* __restrict__ h2last, int* __restrict__ cnts, int* __restrict__ arrive)
{
  constexpr int S1M = FAST ? 31 : 7;   // h1 ring mask
  constexpr int S2M = FAST ? 31 : 3;   // h2 ring mask
  constexpr int BPS = FAST ? 24 : 7;   // L0->L1 backpressure slack

  const int bid   = blockIdx.x;
  const int grp   = bid & 7;           // group co-located per XCD
  const int layer = grp & 1;
  const int bs    = grp >> 1;          // batch slice (16 rows)
  const int ns    = bid >> 3;          // H-chunk (16 cols)
  const int tid   = threadIdx.x;
  const int w     = tid >> 6;          // wave = K-quarter owner
  const int l     = tid & 63;
  const int lm    = l & 15;
  const int ke    = (l >> 4) << 3;
  const int kw4   = w << 2;
  const int kw2   = w << 1;

  int* fbc   = cnts + (bs << 6) * FPAD;                  // group counter base
  int* mycnt = fbc + ((layer << 5) + ns) * FPAD;

  __shared__ float glds[4][4][16][17];

  // startup scrub: wbl2+inv all XCD L2s (poison dirty lines), global barrier
  __builtin_amdgcn_fence(__ATOMIC_SEQ_CST, "agent");
  __syncthreads();
  if (tid == 0) __hip_atomic_fetch_add(arrive, 1, __ATOMIC_RELAXED, SCOPE_AGENT);
  if (tid < 64){
    int spins = 0;
    while (__hip_atomic_load(arrive, __ATOMIC_RELAXED, SCOPE_AGENT) < 256){
      if (++spins > (1<<20)) break;
      __builtin_amdgcn_s_sleep(1);
    }
  }
  __syncthreads();

  #define GCOL(g) ((g<<9) + (ns<<4) + lm)
  const int brow = (bs << 4) + lm;
  const int bl   = tid >> 4, jj = tid & 15;
  const int hcolbase = ns << 4;

  float c_reg = 0.f;
  float bia0, bia1, bia2, bia3;
  {
    const float* bi = layer ? bih1 : bih0;
    const float* bh = layer ? bhh1 : bhh0;
    int c0 = (ns<<4) + jj;
    bia0 = bi[c0]      + bh[c0];
    bia1 = bi[512+c0]  + bh[512+c0];
    bia2 = bi[1024+c0] + bh[1024+c0];
    bia3 = bi[1536+c0] + bh[1536+c0];
  }

  // ---- cell tail: glds-protect barrier -> GWR -> reduce barrier -> gates ->
  //      c,h -> gathered 8B stores -> OWN-wave drain -> counter add ----
  #define GWR(g) { _Pragma("unroll")                                            \
    for (int r = 0; r < 4; r++) glds[w][g][((l>>4)<<2)+r][lm] = p##g[r]; }
  #define CELLX(SLOTBASE, T, LAST)                                              \
  {                                                                             \
    __syncthreads();  /* all waves left previous cell: glds writable */         \
    GWR(0) GWR(1) GWR(2) GWR(3)                                                 \
    __syncthreads();  /* partials ready */                                      \
    float gi = glds[0][0][bl][jj]+glds[1][0][bl][jj]+glds[2][0][bl][jj]+glds[3][0][bl][jj]+bia0; \
    float gf = glds[0][1][bl][jj]+glds[1][1][bl][jj]+glds[2][1][bl][jj]+glds[3][1][bl][jj]+bia1; \
    float gg = glds[0][2][bl][jj]+glds[1][2][bl][jj]+glds[2][2][bl][jj]+glds[3][2][bl][jj]+bia2; \
    float go = glds[0][3][bl][jj]+glds[1][3][bl][jj]+glds[2][3][bl][jj]+glds[3][3][bl][jj]+bia3; \
    float cn = sigm(gf)*c_reg + sigm(gi)*tanhf(gg);                             \
    c_reg = cn;                                                                 \
    float hn  = sigm(go)*tanhf(cn);                                             \
    float hn1 = __shfl_down(hn, 1);                                             \
    unsigned u0  = pack2(hn, hn1),  ul0 = pack2lo(hn, hn1);                     \
    unsigned u1  = __shfl_down(u0, 2), ul1 = __shfl_down(ul0, 2);               \
    if (!(jj & 3)){                                                             \
      short* p = (SLOTBASE) + bl*1024 + hcolbase + jj;                          \
      __hip_atomic_store((unsigned long long*)p,                                \
          (unsigned long long)u0 | ((unsigned long long)u1 << 32),              \
          __ATOMIC_RELAXED, SCOPE_AGENT);                                       \
      __hip_atomic_store((unsigned long long*)(p + 512),                        \
          (unsigned long long)ul0 | ((unsigned long long)ul1 << 32),            \
          __ATOMIC_RELAXED, SCOPE_AGENT);                                       \
    }                                                                           \
    if (LAST)                                                                   \
      __hip_atomic_store(h2last + (size_t)((bs<<4)+bl)*nH + hcolbase + jj, hn,  \
                         __ATOMIC_RELAXED, SCOPE_AGENT);                        \
    asm volatile("s_waitcnt vmcnt(0)" ::: "memory");   /* own wave only */      \
    if (l == 0)                                                                 \
      __hip_atomic_fetch_add(mycnt, 1, __ATOMIC_RELAXED, SCOPE_AGENT);          \
  }

  if (layer == 0){
    #define DWX(g,i) short8 wxh##g##_##i;
    GK2(DWX)
    #define LWX(g,i) wxh##g##_##i = cvt8h(Wih0 + (size_t)GCOL(g)*nD + (kw2+i)*32 + ke);
    GK2(LWX)
    #define DWH(g,i) short8 whh##g##_##i;
    GK4(DWH)
    #define LWH(g,i) whh##g##_##i = cvt8h(Whh0 + (size_t)GCOL(g)*nH + (kw4+i)*32 + ke);
    GK4(LWH)

    // per-wave counter pointers
    const int* ppeer = fbc + ((kw4 << 1) + (l & 7)) * FPAD;        // own 8 L0 producers
    const int* pbp   = fbc + (32 + (l & 31)) * FPAD;               // all 32 L1 (backpressure)

    // x-projection for t=0
    f32x4 xc0={0,0,0,0}, xc1={0,0,0,0}, xc2={0,0,0,0}, xc3={0,0,0,0};
    {
      const float* xb = x + ((size_t)brow*nT)*nD + ke + kw2*32;
      short8 th0, tl0, th1, tl1;
      cvt8(xb, th0, tl0); cvt8(xb + 32, th1, tl1);
      #define XM0(g,i) xc##g = MFMA(th##i, wxh##g##_##i, xc##g);                \
                       xc##g = MFMA(tl##i, wxh##g##_##i, xc##g);
      GK2(XM0)
    }

    int wmbp = -1;                              // L1 progress watermark
    for (int t = 0; t < nT; t++){
      if constexpr (FAST)
        if ((t & 15) == 0) __builtin_amdgcn_fence(__ATOMIC_ACQUIRE, "agent");
      if (wmbp < t - BPS) wmbp = wmN(pbp, 4*(t - BPS + 1));   // rare refresh
      pollN(ppeer, 4*t);                        // own 8 peers at t-1 (no barrier)
      const short* hb = h1r + (size_t)((t+S1M)&S1M)*SLOT_ELEMS + brow*1024;
      #define HLD0(i) short8 vh##i = ldh<FAST>(hb + (kw4+i)*32 + ke);           \
                      short8 vl##i = ldh<FAST>(hb + 512 + (kw4+i)*32 + ke);
      K4(HLD0)
      // x-projection t+1 overlaps h-load latency
      f32x4 xn0={0,0,0,0}, xn1={0,0,0,0}, xn2={0,0,0,0}, xn3={0,0,0,0};
      if (t + 1 < nT){
        const float* xb = x + ((size_t)brow*nT + (t+1))*nD + ke + kw2*32;
        short8 th0, tl0, th1, tl1;
        cvt8(xb, th0, tl0); cvt8(xb + 32, th1, tl1);
        #define XMN(g,i) xn##g = MFMA(th##i, wxh##g##_##i, xn##g);              \
                         xn##g = MFMA(tl##i, wxh##g##_##i, xn##g);
        GK2(XMN)
      }
      // h MFMAs: 4 gates x 4 kk x 2 (hi+lo), four chains per gate
      f32x4 p0a=xc0, p1a=xc1, p2a=xc2, p3a=xc3;
      f32x4 p0b={0,0,0,0}, p1b={0,0,0,0}, p2b={0,0,0,0}, p3b={0,0,0,0};
      f32x4 p0c={0,0,0,0}, p1c={0,0,0,0}, p2c={0,0,0,0}, p3c={0,0,0,0};
      f32x4 p0d={0,0,0,0}, p1d={0,0,0,0}, p2d={0,0,0,0}, p3d={0,0,0,0};
      #define HMM0(g,i) { f32x4& d = (i==0)?p##g##a:((i==1)?p##g##b:((i==2)?p##g##c:p##g##d)); \
        d = MFMA(vh##i, whh##g##_##i, d); d = MFMA(vl##i, whh##g##_##i, d); }
      GK4(HMM0)
      f32x4 p0=(p0a+p0b)+(p0c+p0d), p1=(p1a+p1b)+(p1c+p1d);
      f32x4 p2=(p2a+p2b)+(p2c+p2d), p3=(p3a+p3b)+(p3c+p3d);
      CELLX(h1r + (size_t)(t&S1M)*SLOT_ELEMS + (bs<<4)*1024, t, 0)
      xc0 = xn0; xc1 = xn1; xc2 = xn2; xc3 = xn3;
    }
  } else {
    #define DWA(g,i) short8 ahh##g##_##i;
    GK4(DWA)
    #define LWA(g,i) ahh##g##_##i = cvt8h(Whh1 + (size_t)GCOL(g)*nH + (kw4+i)*32 + ke);
    GK4(LWA)
    #define DWB(g,i) short8 bwh##g##_##i;
    GK4(DWB)
    #define LWB(g,i) bwh##g##_##i = cvt8h(Wih1 + (size_t)GCOL(g)*nH + (kw4+i)*32 + ke);
    GK4(LWB)

    const int* ph1 = fbc + ((kw4 << 1) + (l & 7)) * FPAD;          // 8 L0 producers
    const int* ph2 = fbc + (32 + (kw4 << 1) + (l & 7)) * FPAD;     // own 8 L1 peers

    int wmh1 = -1;                              // L0 progress watermark
    for (int t = 0; t < nT; t++){
      if constexpr (FAST)
        if ((t & 15) == 0) __builtin_amdgcn_fence(__ATOMIC_ACQUIRE, "agent");
      // h1[t] availability: amortized per-wave watermark (L0 runs ~BPS ahead)
      if (wmh1 < t) wmh1 = wmN(ph1, 4*(t + 1));
      // issue h1 loads (latency overlaps the peer poll below)
      const short* h1b = h1r + (size_t)(t&S1M)*SLOT_ELEMS + brow*1024;
      #define HLD1(i) short8 u1h##i = ldh<FAST>(h1b + (kw4+i)*32 + ke);         \
                      short8 u1l##i = ldh<FAST>(h1b + 512 + (kw4+i)*32 + ke);
      K4(HLD1)
      // pacing: own 8 peers at t-1 (no barrier)
      pollN(ph2, 4*t);
      // issue h2 loads (latency overlaps h1 MFMAs)
      const short* h2b = h2r + (size_t)((t+S2M)&S2M)*SLOT_ELEMS + brow*1024;
      #define HLD2(i) short8 u2h##i = ldh<FAST>(h2b + (kw4+i)*32 + ke);         \
                      short8 u2l##i = ldh<FAST>(h2b + 512 + (kw4+i)*32 + ke);
      K4(HLD2)
      f32x4 p0a={0,0,0,0}, p1a={0,0,0,0}, p2a={0,0,0,0}, p3a={0,0,0,0};
      f32x4 p0b={0,0,0,0}, p1b={0,0,0,0}, p2b={0,0,0,0}, p3b={0,0,0,0};
      f32x4 p0c={0,0,0,0}, p1c={0,0,0,0}, p2c={0,0,0,0}, p3c={0,0,0,0};
      f32x4 p0d={0,0,0,0}, p1d={0,0,0,0}, p2d={0,0,0,0}, p3d={0,0,0,0};
      #define HMM1(g,i) { f32x4& d = (i==0)?p##g##a:((i==1)?p##g##b:((i==2)?p##g##c:p##g##d)); \
        d = MFMA(u1h##i, bwh##g##_##i, d); d = MFMA(u1l##i, bwh##g##_##i, d); }
      GK4(HMM1)
      #define HMM2(g,i) { f32x4& d = (i==0)?p##g##a:((i==1)?p##g##b:((i==2)?p##g##c:p##g##d)); \
        d = MFMA(u2h##i, ahh##g##_##i, d); d = MFMA(u2l##i, ahh##g##_##i, d); }
      GK4(HMM2)
      f32x4 p0=(p0a+p0b)+(p0c+p0d), p1=(p1a+p1b)+(p1c+p1d);
      f32x4 p2=(p2a+p2b)+(p2c+p2d), p3=(p3a+p3b)+(p3c+p3d);
      CELLX(h2r + (size_t)(t&S2M)*SLOT_ELEMS + (bs<<4)*1024, t, (t == nT-1))
    }

    // final FC in fp32 VALU (blocks ns<16); per-wave gate on all 32 L1 counters
    if (ns < 16){
      pollN(fbc + (32 + (l & 31)) * FPAD, 4*nT);
      const int orow = (bs<<4) + bl;
      const int ocol = (ns<<4) + jj;
      const unsigned long long* hq = (const unsigned long long*)(h2last + (size_t)orow*nH);
      const float* wr = fcw + (size_t)ocol*nH;
      float s0=0.f, s1=0.f, s2=0.f, s3=0.f;
      #pragma unroll 8
      for (int k = 0; k < nH; k += 8){
        union{ unsigned long long u; float f[2]; } q0,q1,q2,q3;
        q0.u = __hip_atomic_load(hq + (k>>1)    , __ATOMIC_RELAXED, SCOPE_AGENT);
        q1.u = __hip_atomic_load(hq + (k>>1) + 1, __ATOMIC_RELAXED, SCOPE_AGENT);
        q2.u = __hip_atomic_load(hq + (k>>1) + 2, __ATOMIC_RELAXED, SCOPE_AGENT);
        q3.u = __hip_atomic_load(hq + (k>>1) + 3, __ATOMIC_RELAXED, SCOPE_AGENT);
        fvec4 w0 = *(const fvec4*)(wr + k);
        fvec4 w1 = *(const fvec4*)(wr + k + 4);
        s0 += q0.f[0]*w0[0] + q0.f[1]*w0[1];
        s1 += q1.f[0]*w0[2] + q1.f[1]*w0[3];
        s2 += q2.f[0]*w1[0] + q2.f[1]*w1[1];
        s3 += q3.f[0]*w1[2] + q3.f[1]*w1[3];
      }
      out[(size_t)orow*nO + ocol] = s0 + s1 + s2 + s3 + fcb[ocol];
    }
  }
}

extern "C" void kernel_launch(void* const* d_in, const int* in_sizes, int n_in,
                              void* d_out, int out_size, void* d_ws, size_t ws_size,
                              hipStream_t stream)
{
  char* ws = (char*)d_ws;
  int* cnts   = (int*)ws;                          // 256 counters x 128B lines
  int* arrive = (int*)(ws + FLAGS_BYTES);

  size_t need_fast = RING_OFF + 64ull*SLOT_BYTES + (size_t)64*512*4 + 4096;
  const int fast = (ws_size >= need_fast) ? 1 : 0;
  const int s1 = fast ? 32 : 8, s2 = fast ? 32 : 4;

  short* h1r = (short*)(ws + RING_OFF);
  short* h2r = h1r + (size_t)s1 * SLOT_ELEMS;
  float* h2last = (float*)(h2r + (size_t)s2 * SLOT_ELEMS);

  hipMemsetAsync(ws, 0, FLAGS_BYTES, stream);                             // counters = 0
  hipMemsetAsync(ws + FLAGS_BYTES, 0, 64, stream);                        // arrive = 0
  hipMemsetAsync(h1r + (size_t)(s1-1)*SLOT_ELEMS, 0, SLOT_BYTES, stream); // h1[-1]
  hipMemsetAsync(h2r + (size_t)(s2-1)*SLOT_ELEMS, 0, SLOT_BYTES, stream); // h2[-1]

  const float* x    = (const float*)d_in[0];
  const float* Wih0 = (const float*)d_in[1];
  const float* Whh0 = (const float*)d_in[2];
  const float* bih0 = (const float*)d_in[3];
  const float* bhh0 = (const float*)d_in[4];
  const float* Wih1 = (const float*)d_in[5];
  const float* Whh1 = (const float*)d_in[6];
  const float* bih1 = (const float*)d_in[7];
  const float* bhh1 = (const float*)d_in[8];
  const float* fcw  = (const float*)d_in[9];
  const float* fcb  = (const float*)d_in[10];
  float* out = (float*)d_out;

  if (fast)
    lstm_kernel<1><<<256, 256, 0, stream>>>(x, Wih0, Whh0, bih0, bhh0,
        Wih1, Whh1, bih1, bhh1, fcw, fcb, out, h1r, h2r, h2last, cnts, arrive);
  else
    lstm_kernel<0><<<256, 256, 0, stream>>>(x, Wih0, Whh0, bih0, bhh0,
        Wih1, Whh1, bih1, bhh1, fcw, fcb, out, h1r, h2r, h2last, cnts, arrive);
}

// Round 17
// 4081.987 us; speedup vs baseline: 1.2292x; 1.2292x over previous
//
#include <hip/hip_runtime.h>
#include <hip/hip_bf16.h>
#include <stdint.h>

typedef short short8 __attribute__((ext_vector_type(8)));
typedef float f32x4  __attribute__((ext_vector_type(4)));
typedef float fvec4  __attribute__((ext_vector_type(4)));

#define SCOPE_AGENT __HIP_MEMORY_SCOPE_AGENT
#define MFMA(a,b,c) __builtin_amdgcn_mfma_f32_16x16x32_bf16((a),(b),(c),0,0,0)

constexpr int nT = 1024, nD = 256, nH = 512, nO = 256;
constexpr int SLOT_ELEMS = 64 * 1024;                 // 64 rows x (512 hi | 512 lo) bf16
constexpr size_t SLOT_BYTES = (size_t)SLOT_ELEMS * 2; // 128 KiB
constexpr int FPAD = 32;                              // ints per flag (128B line)
constexpr size_t FLAGS_BYTES = 256 * FPAD * 4;        // 32 KiB
constexpr size_t RING_OFF = FLAGS_BYTES + 8192;
constexpr int NEG = -0x40000000;

// R16 post-mortem: barrier-free counter protocol regressed +23% (fetch_add
// RMW serialization on counter lines, 4x poll traffic, 3 barrier regions).
// R17 = exact revert to R15, the empirical best (4086us):
//  - wave0 polls padded block-flags, waves 1-3 park at barrier
//  - L1: cached L0 watermark + h1-phase off the pacing chain
//  - gathered 8B stores, one post-store barrier, single tid0 flag store
// Remaining ~4us/step = 1024 serial LLC rendezvous (flag visibility + detect
// + h RT) x straggler-max over 32 producers: the latency floor for this
// communication pattern at agent scope on this chip.
#define K4(M)  M(0) M(1) M(2) M(3)
#define GK2(M) M(0,0) M(1,0) M(2,0) M(3,0) M(0,1) M(1,1) M(2,1) M(3,1)
#define GK4(M) GK2(M) M(0,2) M(1,2) M(2,2) M(3,2) M(0,3) M(1,3) M(2,3) M(3,3)

__device__ __forceinline__ float sigm(float x){ return 1.f/(1.f + __expf(-x)); }

__device__ __forceinline__ short8 cvt8h(const float* p){
  fvec4 a = *(const fvec4*)p;
  fvec4 b = *(const fvec4*)(p + 4);
  short8 hi;
  #pragma unroll
  for (int j = 0; j < 8; j++){
    float v = (j < 4) ? a[j] : b[j-4];
    hi[j] = (short)__bfloat16_as_ushort(__float2bfloat16(v));
  }
  return hi;
}
__device__ __forceinline__ void cvt8(const float* p, short8& hi, short8& lo){
  fvec4 a = *(const fvec4*)p;
  fvec4 b = *(const fvec4*)(p + 4);
  #pragma unroll
  for (int j = 0; j < 8; j++){
    float v = (j < 4) ? a[j] : b[j-4];
    __hip_bfloat16 h = __float2bfloat16(v);
    float r = v - __bfloat162float(h);
    hi[j] = (short)__bfloat16_as_ushort(h);
    lo[j] = (short)__bfloat16_as_ushort(__float2bfloat16(r));
  }
}
__device__ __forceinline__ unsigned pack2(float a, float b){
  return (unsigned)__bfloat16_as_ushort(__float2bfloat16(a)) |
         ((unsigned)__bfloat16_as_ushort(__float2bfloat16(b)) << 16);
}
__device__ __forceinline__ unsigned pack2lo(float a, float b){
  float ra = a - __bfloat162float(__float2bfloat16(a));
  float rb = b - __bfloat162float(__float2bfloat16(b));
  return pack2(ra, rb);
}

// h load: FAST = plain cached (L2-shareable); slow = agent atomic (proven)
template<int FAST>
__device__ __forceinline__ short8 ldh(const short* p){
  if constexpr (FAST){
    return *(const short8*)p;
  } else {
    union { unsigned long long u[2]; short8 v; } r;
    const unsigned long long* q = (const unsigned long long*)p;
    r.u[0] = __hip_atomic_load(q,     __ATOMIC_RELAXED, SCOPE_AGENT);
    r.u[1] = __hip_atomic_load(q + 1, __ATOMIC_RELAXED, SCOPE_AGENT);
    return r.v;
  }
}

// Wave 0 polls 64 padded block-flags (lanes 0..31: layer-0, 32..63: layer-1);
// waves 1-3 park at the barrier. One flag per 128B line.
__device__ __forceinline__ void poll(const int* fb, int t0, int t1){
  if (threadIdx.x < 64){
    int lid = threadIdx.x;
    int tgt = (lid < 32) ? t0 : t1;
    const int* p = fb + lid * FPAD;
    int spins = 0;
    for(;;){
      int v = __hip_atomic_load(p, __ATOMIC_RELAXED, SCOPE_AGENT);
      if (__all(v >= tgt)) break;
      if (++spins > (1<<17)) break;                // fail-safe, never hang
      if (spins > 64) __builtin_amdgcn_s_sleep(1);
    }
  }
  __syncthreads();
}

// Poll L0 flags (32, lanes 0-31) until >= tgt; return MIN observed watermark
// (broadcast via LDS). Used by L1 to cache L0 progress (~24 ahead) so the
// h1-availability check costs nothing on most steps.
__device__ __forceinline__ int poll_min(const int* fb, int tgt, int* sv){
  if (threadIdx.x < 64){
    int lid = threadIdx.x;
    int v = 0x7FFFFFFF;
    if (lid < 32){
      const int* p = fb + lid * FPAD;
      v = __hip_atomic_load(p, __ATOMIC_RELAXED, SCOPE_AGENT);
      int spins = 0;
      while (v < tgt){
        if (++spins > (1<<17)) break;
        if (spins > 64) __builtin_amdgcn_s_sleep(1);
        v = __hip_atomic_load(p, __ATOMIC_RELAXED, SCOPE_AGENT);
      }
    }
    int m = v;
    #pragma unroll
    for (int off = 16; off; off >>= 1) m = min(m, __shfl_down(m, off));
    if (lid == 0) sv[0] = m;
  }
  __syncthreads();
  return sv[0];
}

template<int FAST>
__global__ __launch_bounds__(256, 1)
__attribute__((amdgpu_waves_per_eu(1, 1)))
void lstm_kernel(
    const float* __restrict__ x,
    const float* __restrict__ Wih0, const float* __restrict__ Whh0,
    const float* __restrict__ bih0, const float* __restrict__ bhh0,
    const float* __restrict__ Wih1, const float* __restrict__ Whh1,
    const float* __restrict__ bih1, const float* __restrict__ bhh1,
    const float* __restrict__ fcw, const float* __restrict__ fcb,
    float* __restrict__ out,
    short* __restrict__ h1r, short* __restrict__ h2r,
    float* __restrict__ h2last, int* __restrict__ flags, int* __restrict__ arrive)
{
  constexpr int S1M = FAST ? 31 : 7;   // h1 ring mask
  constexpr int S2M = FAST ? 31 : 3;   // h2 ring mask
  constexpr int BPS = FAST ? 24 : 7;   // L0->L1 backpressure slack

  const int bid   = blockIdx.x;
  const int grp   = bid & 7;           // group co-located per XCD
  const int layer = grp & 1;
  const int bs    = grp >> 1;          // batch slice (16 rows)
  const int ns    = bid >> 3;          // H-chunk (16 cols)
  const int tid   = threadIdx.x;
  const int w     = tid >> 6;          // wave = K-quarter owner
  const int l     = tid & 63;
  const int lm    = l & 15;
  const int ke    = (l >> 4) << 3;
  const int kw4   = w << 2;
  const int kw2   = w << 1;

  int* fb     = flags + (bs << 6) * FPAD;
  int* myflag = fb + ((layer << 5) + ns) * FPAD;

  __shared__ float glds[4][4][16][17];
  __shared__ int svv[2];

  // startup scrub: wbl2+inv all XCD L2s (poison dirty lines), global barrier
  __builtin_amdgcn_fence(__ATOMIC_SEQ_CST, "agent");
  __syncthreads();
  if (tid == 0) __hip_atomic_fetch_add(arrive, 1, __ATOMIC_RELAXED, SCOPE_AGENT);
  if (tid < 64){
    int spins = 0;
    while (__hip_atomic_load(arrive, __ATOMIC_RELAXED, SCOPE_AGENT) < 256){
      if (++spins > (1<<20)) break;
      __builtin_amdgcn_s_sleep(1);
    }
  }
  __syncthreads();

  #define GCOL(g) ((g<<9) + (ns<<4) + lm)
  const int brow = (bs << 4) + lm;
  const int bl   = tid >> 4, jj = tid & 15;
  const int hcolbase = ns << 4;

  float c_reg = 0.f;
  float bia0, bia1, bia2, bia3;
  {
    const float* bi = layer ? bih1 : bih0;
    const float* bh = layer ? bhh1 : bhh0;
    int c0 = (ns<<4) + jj;
    bia0 = bi[c0]      + bh[c0];
    bia1 = bi[512+c0]  + bh[512+c0];
    bia2 = bi[1024+c0] + bh[1024+c0];
    bia3 = bi[1536+c0] + bh[1536+c0];
  }

  // ---- cell update: LDS-reduce wave partials -> gates -> c,h ->
  //      gathered 8B ring stores -> barrier -> padded block flag ----
  #define GWR(g) { _Pragma("unroll")                                            \
    for (int r = 0; r < 4; r++) glds[w][g][((l>>4)<<2)+r][lm] = p##g[r]; }
  #define CELLX(SLOTBASE, T, LAST)                                              \
  {                                                                             \
    GWR(0) GWR(1) GWR(2) GWR(3)                                                 \
    __syncthreads();                                                            \
    float gi = glds[0][0][bl][jj]+glds[1][0][bl][jj]+glds[2][0][bl][jj]+glds[3][0][bl][jj]+bia0; \
    float gf = glds[0][1][bl][jj]+glds[1][1][bl][jj]+glds[2][1][bl][jj]+glds[3][1][bl][jj]+bia1; \
    float gg = glds[0][2][bl][jj]+glds[1][2][bl][jj]+glds[2][2][bl][jj]+glds[3][2][bl][jj]+bia2; \
    float go = glds[0][3][bl][jj]+glds[1][3][bl][jj]+glds[2][3][bl][jj]+glds[3][3][bl][jj]+bia3; \
    float cn = sigm(gf)*c_reg + sigm(gi)*tanhf(gg);                             \
    c_reg = cn;                                                                 \
    float hn  = sigm(go)*tanhf(cn);                                             \
    float hn1 = __shfl_down(hn, 1);                                             \
    unsigned u0  = pack2(hn, hn1),  ul0 = pack2lo(hn, hn1);                     \
    unsigned u1  = __shfl_down(u0, 2), ul1 = __shfl_down(ul0, 2);               \
    if (!(jj & 3)){                                                             \
      short* p = (SLOTBASE) + bl*1024 + hcolbase + jj;                          \
      __hip_atomic_store((unsigned long long*)p,                                \
          (unsigned long long)u0 | ((unsigned long long)u1 << 32),              \
          __ATOMIC_RELAXED, SCOPE_AGENT);                                       \
      __hip_atomic_store((unsigned long long*)(p + 512),                        \
          (unsigned long long)ul0 | ((unsigned long long)ul1 << 32),            \
          __ATOMIC_RELAXED, SCOPE_AGENT);                                       \
    }                                                                           \
    if (LAST)                                                                   \
      __hip_atomic_store(h2last + (size_t)((bs<<4)+bl)*nH + hcolbase + jj, hn,  \
                         __ATOMIC_RELAXED, SCOPE_AGENT);                        \
    __syncthreads();  /* compiler drains vmcnt(0) before s_barrier */           \
    if (tid == 0)                                                               \
      __hip_atomic_store(myflag, (T), __ATOMIC_RELAXED, SCOPE_AGENT);           \
  }

  if (layer == 0){
    #define DWX(g,i) short8 wxh##g##_##i;
    GK2(DWX)
    #define LWX(g,i) wxh##g##_##i = cvt8h(Wih0 + (size_t)GCOL(g)*nD + (kw2+i)*32 + ke);
    GK2(LWX)
    #define DWH(g,i) short8 whh##g##_##i;
    GK4(DWH)
    #define LWH(g,i) whh##g##_##i = cvt8h(Whh0 + (size_t)GCOL(g)*nH + (kw4+i)*32 + ke);
    GK4(LWH)

    // x-projection for t=0
    f32x4 xc0={0,0,0,0}, xc1={0,0,0,0}, xc2={0,0,0,0}, xc3={0,0,0,0};
    {
      const float* xb = x + ((size_t)brow*nT)*nD + ke + kw2*32;
      short8 th0, tl0, th1, tl1;
      cvt8(xb, th0, tl0); cvt8(xb + 32, th1, tl1);
      #define XM0(g,i) xc##g = MFMA(th##i, wxh##g##_##i, xc##g);                \
                       xc##g = MFMA(tl##i, wxh##g##_##i, xc##g);
      GK2(XM0)
    }

    for (int t = 0; t < nT; t++){
      poll(fb, t-1, t-BPS);                     // L0 peers t-1; L1 backpressure
      if constexpr (FAST)
        if ((t & 15) == 0) __builtin_amdgcn_fence(__ATOMIC_ACQUIRE, "agent");
      const short* hb = h1r + (size_t)((t+S1M)&S1M)*SLOT_ELEMS + brow*1024;
      #define HLD0(i) short8 vh##i = ldh<FAST>(hb + (kw4+i)*32 + ke);           \
                      short8 vl##i = ldh<FAST>(hb + 512 + (kw4+i)*32 + ke);
      K4(HLD0)
      // x-projection t+1 overlaps h-load latency
      f32x4 xn0={0,0,0,0}, xn1={0,0,0,0}, xn2={0,0,0,0}, xn3={0,0,0,0};
      if (t + 1 < nT){
        const float* xb = x + ((size_t)brow*nT + (t+1))*nD + ke + kw2*32;
        short8 th0, tl0, th1, tl1;
        cvt8(xb, th0, tl0); cvt8(xb + 32, th1, tl1);
        #define XMN(g,i) xn##g = MFMA(th##i, wxh##g##_##i, xn##g);              \
                         xn##g = MFMA(tl##i, wxh##g##_##i, xn##g);
        GK2(XMN)
      }
      // h MFMAs: 4 gates x 4 kk x 2 (hi+lo), four chains per gate
      f32x4 p0a=xc0, p1a=xc1, p2a=xc2, p3a=xc3;
      f32x4 p0b={0,0,0,0}, p1b={0,0,0,0}, p2b={0,0,0,0}, p3b={0,0,0,0};
      f32x4 p0c={0,0,0,0}, p1c={0,0,0,0}, p2c={0,0,0,0}, p3c={0,0,0,0};
      f32x4 p0d={0,0,0,0}, p1d={0,0,0,0}, p2d={0,0,0,0}, p3d={0,0,0,0};
      #define HMM0(g,i) { f32x4& d = (i==0)?p##g##a:((i==1)?p##g##b:((i==2)?p##g##c:p##g##d)); \
        d = MFMA(vh##i, whh##g##_##i, d); d = MFMA(vl##i, whh##g##_##i, d); }
      GK4(HMM0)
      f32x4 p0=(p0a+p0b)+(p0c+p0d), p1=(p1a+p1b)+(p1c+p1d);
      f32x4 p2=(p2a+p2b)+(p2c+p2d), p3=(p3a+p3b)+(p3c+p3d);
      CELLX(h1r + (size_t)(t&S1M)*SLOT_ELEMS + (bs<<4)*1024, t, 0)
      xc0 = xn0; xc1 = xn1; xc2 = xn2; xc3 = xn3;
    }
  } else {
    #define DWA(g,i) short8 ahh##g##_##i;
    GK4(DWA)
    #define LWA(g,i) ahh##g##_##i = cvt8h(Whh1 + (size_t)GCOL(g)*nH + (kw4+i)*32 + ke);
    GK4(LWA)
    #define DWB(g,i) short8 bwh##g##_##i;
    GK4(DWB)
    #define LWB(g,i) bwh##g##_##i = cvt8h(Wih1 + (size_t)GCOL(g)*nH + (kw4+i)*32 + ke);
    GK4(LWB)

    int l0min = -1;                     // cached L0 progress watermark
    for (int t = 0; t < nT; t++){
      if constexpr (FAST)
        if ((t & 15) == 0) __builtin_amdgcn_fence(__ATOMIC_ACQUIRE, "agent");
      // h1[t] availability: amortized check (L0 runs ~BPS ahead)
      if (l0min < t) l0min = poll_min(fb, t, &svv[t & 1]);
      // issue h1 loads (latency overlaps the peer poll below)
      const short* h1b = h1r + (size_t)(t&S1M)*SLOT_ELEMS + brow*1024;
      #define HLD1(i) short8 u1h##i = ldh<FAST>(h1b + (kw4+i)*32 + ke);         \
                      short8 u1l##i = ldh<FAST>(h1b + 512 + (kw4+i)*32 + ke);
      K4(HLD1)
      // pacing dependency: own peers at t-1
      poll(fb, NEG, t-1);
      // issue h2 loads (latency overlaps h1 MFMAs)
      const short* h2b = h2r + (size_t)((t+S2M)&S2M)*SLOT_ELEMS + brow*1024;
      #define HLD2(i) short8 u2h##i = ldh<FAST>(h2b + (kw4+i)*32 + ke);         \
                      short8 u2l##i = ldh<FAST>(h2b + 512 + (kw4+i)*32 + ke);
      K4(HLD2)
      f32x4 p0a={0,0,0,0}, p1a={0,0,0,0}, p2a={0,0,0,0}, p3a={0,0,0,0};
      f32x4 p0b={0,0,0,0}, p1b={0,0,0,0}, p2b={0,0,0,0}, p3b={0,0,0,0};
      f32x4 p0c={0,0,0,0}, p1c={0,0,0,0}, p2c={0,0,0,0}, p3c={0,0,0,0};
      f32x4 p0d={0,0,0,0}, p1d={0,0,0,0}, p2d={0,0,0,0}, p3d={0,0,0,0};
      #define HMM1(g,i) { f32x4& d = (i==0)?p##g##a:((i==1)?p##g##b:((i==2)?p##g##c:p##g##d)); \
        d = MFMA(u1h##i, bwh##g##_##i, d); d = MFMA(u1l##i, bwh##g##_##i, d); }
      GK4(HMM1)
      #define HMM2(g,i) { f32x4& d = (i==0)?p##g##a:((i==1)?p##g##b:((i==2)?p##g##c:p##g##d)); \
        d = MFMA(u2h##i, ahh##g##_##i, d); d = MFMA(u2l##i, ahh##g##_##i, d); }
      GK4(HMM2)
      f32x4 p0=(p0a+p0b)+(p0c+p0d), p1=(p1a+p1b)+(p1c+p1d);
      f32x4 p2=(p2a+p2b)+(p2c+p2d), p3=(p3a+p3b)+(p3c+p3d);
      CELLX(h2r + (size_t)(t&S2M)*SLOT_ELEMS + (bs<<4)*1024, t, (t == nT-1))
    }

    // final FC in fp32 VALU (blocks ns<16)
    if (ns < 16){
      poll(fb, NEG, nT-1);
      const int orow = (bs<<4) + bl;
      const int ocol = (ns<<4) + jj;
      const unsigned long long* hq = (const unsigned long long*)(h2last + (size_t)orow*nH);
      const float* wr = fcw + (size_t)ocol*nH;
      float s0=0.f, s1=0.f, s2=0.f, s3=0.f;
      #pragma unroll 8
      for (int k = 0; k < nH; k += 8){
        union{ unsigned long long u; float f[2]; } q0,q1,q2,q3;
        q0.u = __hip_atomic_load(hq + (k>>1)    , __ATOMIC_RELAXED, SCOPE_AGENT);
        q1.u = __hip_atomic_load(hq + (k>>1) + 1, __ATOMIC_RELAXED, SCOPE_AGENT);
        q2.u = __hip_atomic_load(hq + (k>>1) + 2, __ATOMIC_RELAXED, SCOPE_AGENT);
        q3.u = __hip_atomic_load(hq + (k>>1) + 3, __ATOMIC_RELAXED, SCOPE_AGENT);
        fvec4 w0 = *(const fvec4*)(wr + k);
        fvec4 w1 = *(const fvec4*)(wr + k + 4);
        s0 += q0.f[0]*w0[0] + q0.f[1]*w0[1];
        s1 += q1.f[0]*w0[2] + q1.f[1]*w0[3];
        s2 += q2.f[0]*w1[0] + q2.f[1]*w1[1];
        s3 += q3.f[0]*w1[2] + q3.f[1]*w1[3];
      }
      out[(size_t)orow*nO + ocol] = s0 + s1 + s2 + s3 + fcb[ocol];
    }
  }
}

extern "C" void kernel_launch(void* const* d_in, const int* in_sizes, int n_in,
                              void* d_out, int out_size, void* d_ws, size_t ws_size,
                              hipStream_t stream)
{
  char* ws = (char*)d_ws;
  int* flags  = (int*)ws;                          // 256 flags x 128B lines
  int* arrive = (int*)(ws + FLAGS_BYTES);

  size_t need_fast = RING_OFF + 64ull*SLOT_BYTES + (size_t)64*512*4 + 4096;
  const int fast = (ws_size >= need_fast) ? 1 : 0;
  const int s1 = fast ? 32 : 8, s2 = fast ? 32 : 4;

  short* h1r = (short*)(ws + RING_OFF);
  short* h2r = h1r + (size_t)s1 * SLOT_ELEMS;
  float* h2last = (float*)(h2r + (size_t)s2 * SLOT_ELEMS);

  hipMemsetAsync(ws, 0xFF, FLAGS_BYTES, stream);                          // flags = -1
  hipMemsetAsync(ws + FLAGS_BYTES, 0, 64, stream);                        // arrive = 0
  hipMemsetAsync(h1r + (size_t)(s1-1)*SLOT_ELEMS, 0, SLOT_BYTES, stream); // h1[-1]
  hipMemsetAsync(h2r + (size_t)(s2-1)*SLOT_ELEMS, 0, SLOT_BYTES, stream); // h2[-1]

  const float* x    = (const float*)d_in[0];
  const float* Wih0 = (const float*)d_in[1];
  const float* Whh0 = (const float*)d_in[2];
  const float* bih0 = (const float*)d_in[3];
  const float* bhh0 = (const float*)d_in[4];
  const float* Wih1 = (const float*)d_in[5];
  const float* Whh1 = (const float*)d_in[6];
  const float* bih1 = (const float*)d_in[7];
  const float* bhh1 = (const float*)d_in[8];
  const float* fcw  = (const float*)d_in[9];
  const float* fcb  = (const float*)d_in[10];
  float* out = (float*)d_out;

  if (fast)
    lstm_kernel<1><<<256, 256, 0, stream>>>(x, Wih0, Whh0, bih0, bhh0,
        Wih1, Whh1, bih1, bhh1, fcw, fcb, out, h1r, h2r, h2last, flags, arrive);
  else
    lstm_kernel<0><<<256, 256, 0, stream>>>(x, Wih0, Whh0, bih0, bhh0,
        Wih1, Whh1, bih1, bhh1, fcw, fcb, out, h1r, h2r, h2last, flags, arrive);
}